// Round 1
// baseline (1114.474 us; speedup 1.0000x reference)
//
#include <hip/hip_runtime.h>

constexpr int XD = 48;   // geom feature dim
constexpr int HD = 96;   // hidden dim (= 2*XD)
constexpr int BT = 128;  // threads per block

__global__ void __launch_bounds__(BT) collision_kernel(
    const int* __restrict__ o1, const int* __restrict__ o2,
    const float* __restrict__ Tg, const float* __restrict__ geoms,
    const float* __restrict__ W1, const float* __restrict__ b1,
    const float* __restrict__ W2, const float* __restrict__ b2,
    const float* __restrict__ W3, const float* __restrict__ b3,
    float* __restrict__ out, int N)
{
    // per-thread activation scratch, transposed [k][tid]: lane-consecutive -> conflict-free
    __shared__ float xs[HD][BT];
    const int tid  = threadIdx.x;
    const int pair = blockIdx.x * BT + tid;
    if (pair >= N) return;

    // ---- load T (row-major 4x4) ----
    float Tm[16];
    {
        const float4* T4 = reinterpret_cast<const float4*>(Tg + (size_t)pair * 16);
        #pragma unroll
        for (int r = 0; r < 4; ++r) {
            float4 t = T4[r];
            Tm[4*r+0] = t.x; Tm[4*r+1] = t.y; Tm[4*r+2] = t.z; Tm[4*r+3] = t.w;
        }
    }

    // ---- 4x4 inverse in double (adjugate/cofactors); keep rows 0..2 as float [3x4] ----
    float Ti[12];
    {
        double m00=Tm[0],  m01=Tm[1],  m02=Tm[2],  m03=Tm[3];
        double m10=Tm[4],  m11=Tm[5],  m12=Tm[6],  m13=Tm[7];
        double m20=Tm[8],  m21=Tm[9],  m22=Tm[10], m23=Tm[11];
        double m30=Tm[12], m31=Tm[13], m32=Tm[14], m33=Tm[15];
        double A2323 = m22*m33 - m23*m32;
        double A1323 = m21*m33 - m23*m31;
        double A1223 = m21*m32 - m22*m31;
        double A0323 = m20*m33 - m23*m30;
        double A0223 = m20*m32 - m22*m30;
        double A0123 = m20*m31 - m21*m30;
        double A2313 = m12*m33 - m13*m32;
        double A1313 = m11*m33 - m13*m31;
        double A1213 = m11*m32 - m12*m31;
        double A2312 = m12*m23 - m13*m22;
        double A1312 = m11*m23 - m13*m21;
        double A1212 = m11*m22 - m12*m21;
        double A0313 = m10*m33 - m13*m30;
        double A0213 = m10*m32 - m12*m30;
        double A0312 = m10*m23 - m13*m20;
        double A0212 = m10*m22 - m12*m20;
        double A0113 = m10*m31 - m11*m30;
        double A0112 = m10*m21 - m11*m20;
        double det = m00*(m11*A2323 - m12*A1323 + m13*A1223)
                   - m01*(m10*A2323 - m12*A0323 + m13*A0223)
                   + m02*(m10*A1323 - m11*A0323 + m13*A0123)
                   - m03*(m10*A1223 - m11*A0223 + m12*A0123);
        double idet = 1.0 / det;
        Ti[0]  = (float)( idet *  (m11*A2323 - m12*A1323 + m13*A1223) );
        Ti[1]  = (float)( idet * -(m01*A2323 - m02*A1323 + m03*A1223) );
        Ti[2]  = (float)( idet *  (m01*A2313 - m02*A1313 + m03*A1213) );
        Ti[3]  = (float)( idet * -(m01*A2312 - m02*A1312 + m03*A1212) );
        Ti[4]  = (float)( idet * -(m10*A2323 - m12*A0323 + m13*A0223) );
        Ti[5]  = (float)( idet *  (m00*A2323 - m02*A0323 + m03*A0223) );
        Ti[6]  = (float)( idet * -(m00*A2313 - m02*A0313 + m03*A0213) );
        Ti[7]  = (float)( idet *  (m00*A2312 - m02*A0312 + m03*A0212) );
        Ti[8]  = (float)( idet *  (m10*A1323 - m11*A0323 + m13*A0123) );
        Ti[9]  = (float)( idet * -(m00*A1323 - m01*A0323 + m03*A0123) );
        Ti[10] = (float)( idet *  (m00*A1313 - m01*A0313 + m03*A0113) );
        Ti[11] = (float)( idet * -(m00*A1312 - m01*A0312 + m03*A0112) );
    }
    // forward transform rows 0..2 as float [3x4]
    float Tf[12];
    #pragma unroll
    for (int i = 0; i < 12; ++i) Tf[i] = Tm[i];

    const int i1 = o1[pair];
    const int i2 = o2[pair];
    const float4* g1p = reinterpret_cast<const float4*>(geoms + (size_t)i1 * XD);
    const float4* g2p = reinterpret_cast<const float4*>(geoms + (size_t)i2 * XD);

    // build x = [ a , M o b ] into xs[.][tid]; M is 3x4 row-major (R|t)
    auto build = [&](const float4* ap, const float4* bp, const float* M) {
        #pragma unroll
        for (int q = 0; q < 12; ++q) {
            float4 t = ap[q];
            xs[4*q+0][tid] = t.x; xs[4*q+1][tid] = t.y;
            xs[4*q+2][tid] = t.z; xs[4*q+3][tid] = t.w;
        }
        float v[XD];
        #pragma unroll
        for (int q = 0; q < 12; ++q) {
            float4 t = bp[q];
            v[4*q+0] = t.x; v[4*q+1] = t.y; v[4*q+2] = t.z; v[4*q+3] = t.w;
        }
        #pragma unroll
        for (int m = 0; m < 16; ++m) {
            float vx = v[3*m+0], vy = v[3*m+1], vz = v[3*m+2];
            #pragma unroll
            for (int i = 0; i < 3; ++i) {
                xs[XD+3*m+i][tid] =
                    fmaf(M[4*i+0], vx, fmaf(M[4*i+1], vy, fmaf(M[4*i+2], vz, M[4*i+3])));
            }
        }
    };

    // MLP on xs[.][tid]; h accumulators in regs, inner j unrolled, outer k rolled
    auto mlp = [&]() -> float {
        float h[HD];
        #pragma unroll
        for (int j = 0; j < HD; ++j) h[j] = b1[j];
        #pragma unroll 2
        for (int k = 0; k < HD; ++k) {
            float xk = xs[k][tid];
            #pragma unroll
            for (int j = 0; j < HD; ++j) h[j] = fmaf(xk, W1[k*HD+j], h[j]);
        }
        #pragma unroll
        for (int j = 0; j < HD; ++j) xs[j][tid] = fmaxf(h[j], 0.0f);
        #pragma unroll
        for (int j = 0; j < HD; ++j) h[j] = b2[j];
        #pragma unroll 2
        for (int k = 0; k < HD; ++k) {
            float xk = xs[k][tid];
            #pragma unroll
            for (int j = 0; j < HD; ++j) h[j] = fmaf(xk, W2[k*HD+j], h[j]);
        }
        float y = b3[0];
        #pragma unroll
        for (int j = 0; j < HD; ++j) y = fmaf(fmaxf(h[j], 0.0f), W3[j], y);
        return y;
    };

    build(g1p, g2p, Tf);
    float ya = mlp();
    build(g2p, g1p, Ti);
    float yb = mlp();

    out[pair] = 0.5f * (ya + yb);
}

extern "C" void kernel_launch(void* const* d_in, const int* in_sizes, int n_in,
                              void* d_out, int out_size, void* d_ws, size_t ws_size,
                              hipStream_t stream) {
    const int*   o1    = (const int*)d_in[0];
    const int*   o2    = (const int*)d_in[1];
    const float* T     = (const float*)d_in[2];
    const float* geoms = (const float*)d_in[3];
    const float* W1    = (const float*)d_in[4];
    const float* b1    = (const float*)d_in[5];
    const float* W2    = (const float*)d_in[6];
    const float* b2    = (const float*)d_in[7];
    const float* W3    = (const float*)d_in[8];
    const float* b3    = (const float*)d_in[9];
    float* out = (float*)d_out;
    const int N = in_sizes[0];

    dim3 grid((N + BT - 1) / BT), block(BT);
    hipLaunchKernelGGL(collision_kernel, grid, block, 0, stream,
                       o1, o2, T, geoms, W1, b1, W2, b2, W3, b3, out, N);
}

// Round 2
// 212.618 us; speedup vs baseline: 5.2417x; 5.2417x over previous
//
#include <hip/hip_runtime.h>

typedef __attribute__((ext_vector_type(8))) short bf16x8;
typedef __attribute__((ext_vector_type(4))) float f32x4;

constexpr int BT   = 256;   // threads/block (4 waves)
constexpr int TP   = 64;    // pairs per tile
constexpr int TR   = 128;   // rows per tile (2 branches per pair)
constexpr int KD   = 96;    // feature/hidden dim
constexpr int LDX  = 104;   // padded row stride in bf16 elems (208 B = 13*16B)
constexpr int NBLK = 512;   // persistent blocks (2 per CU)

__device__ inline ushort f2bf(float f) {  // fp32 -> bf16 RNE
    uint u = __float_as_uint(f);
    u += 0x7fffu + ((u >> 16) & 1u);
    return (ushort)(u >> 16);
}

__global__ void __launch_bounds__(BT, 2) collision_mfma(
    const int* __restrict__ o1, const int* __restrict__ o2,
    const float* __restrict__ Tg, const float* __restrict__ geoms,
    const float* __restrict__ W1, const float* __restrict__ b1,
    const float* __restrict__ W2, const float* __restrict__ b2,
    const float* __restrict__ W3, const float* __restrict__ b3,
    float* __restrict__ out, int N)
{
    __shared__ ushort xs[TR * LDX];    // x tile / h tile (bf16), 26624 B
    __shared__ ushort w1t[KD * LDX];   // W1^T bf16, 19968 B
    __shared__ ushort w2t[KD * LDX];   // W2^T bf16, 19968 B
    __shared__ float  tinv[TP][13];    // per-pair inverse rows 0..2 (3x4)

    const int tid = threadIdx.x;

    // ---- stage weights once: Wt[n][k] = W[k][n], bf16 ----
    for (int i = tid; i < KD * KD; i += BT) {
        int k = i / KD;
        int n = i - k * KD;
        w1t[n * LDX + k] = f2bf(W1[i]);
        w2t[n * LDX + k] = f2bf(W2[i]);
    }
    __syncthreads();

    const int w  = tid >> 6;       // wave id 0..3
    const int l  = tid & 63;       // lane
    const int cl = l & 15;         // fragment col
    const int rg = (l >> 4) * 4;   // fragment row group

    const int ntiles = N / TP;

    for (int tile = blockIdx.x; tile < ntiles; tile += NBLK) {
        // ===== phase 1: f64 4x4 inverse, lanes 0..15 of each wave, 1 pair/lane =====
        if (l < 16) {
            const int p = tile * TP + w * 16 + l;
            const float4* T4 = reinterpret_cast<const float4*>(Tg + (size_t)p * 16);
            float4 t0 = T4[0], t1 = T4[1], t2 = T4[2], t3 = T4[3];
            double m00=t0.x, m01=t0.y, m02=t0.z, m03=t0.w;
            double m10=t1.x, m11=t1.y, m12=t1.z, m13=t1.w;
            double m20=t2.x, m21=t2.y, m22=t2.z, m23=t2.w;
            double m30=t3.x, m31=t3.y, m32=t3.z, m33=t3.w;
            double A2323 = m22*m33 - m23*m32;
            double A1323 = m21*m33 - m23*m31;
            double A1223 = m21*m32 - m22*m31;
            double A0323 = m20*m33 - m23*m30;
            double A0223 = m20*m32 - m22*m30;
            double A0123 = m20*m31 - m21*m30;
            double A2313 = m12*m33 - m13*m32;
            double A1313 = m11*m33 - m13*m31;
            double A1213 = m11*m32 - m12*m31;
            double A2312 = m12*m23 - m13*m22;
            double A1312 = m11*m23 - m13*m21;
            double A1212 = m11*m22 - m12*m21;
            double A0313 = m10*m33 - m13*m30;
            double A0213 = m10*m32 - m12*m30;
            double A0312 = m10*m23 - m13*m20;
            double A0212 = m10*m22 - m12*m20;
            double A0113 = m10*m31 - m11*m30;
            double A0112 = m10*m21 - m11*m20;
            double det = m00*(m11*A2323 - m12*A1323 + m13*A1223)
                       - m01*(m10*A2323 - m12*A0323 + m13*A0223)
                       + m02*(m10*A1323 - m11*A0323 + m13*A0123)
                       - m03*(m10*A1223 - m11*A0223 + m12*A0123);
            double idet = 1.0 / det;
            float* ti = tinv[w * 16 + l];
            ti[0]  = (float)( idet *  (m11*A2323 - m12*A1323 + m13*A1223) );
            ti[1]  = (float)( idet * -(m01*A2323 - m02*A1323 + m03*A1223) );
            ti[2]  = (float)( idet *  (m01*A2313 - m02*A1313 + m03*A1213) );
            ti[3]  = (float)( idet * -(m01*A2312 - m02*A1312 + m03*A1212) );
            ti[4]  = (float)( idet * -(m10*A2323 - m12*A0323 + m13*A0223) );
            ti[5]  = (float)( idet *  (m00*A2323 - m02*A0323 + m03*A0223) );
            ti[6]  = (float)( idet * -(m00*A2313 - m02*A0313 + m03*A0213) );
            ti[7]  = (float)( idet *  (m00*A2312 - m02*A0312 + m03*A0212) );
            ti[8]  = (float)( idet *  (m10*A1323 - m11*A0323 + m13*A0123) );
            ti[9]  = (float)( idet * -(m00*A1323 - m01*A0323 + m03*A0123) );
            ti[10] = (float)( idet *  (m00*A1313 - m01*A0313 + m03*A0113) );
            ti[11] = (float)( idet * -(m00*A1312 - m01*A0312 + m03*A0112) );
        }
        __syncthreads();

        // ===== phase 2: stage x tile (bf16). 2 threads per row. =====
        {
            const int rl  = l >> 1;            // 0..31 local row within wave's rows
            const int row = w * 32 + rl;       // tile-local row; wave-private band
            const int dp  = rl >> 1;           // local pair 0..15
            const int p   = tile * TP + w * 16 + dp;
            const int br  = rl & 1;            // branch: 0 = (x1,[T]x2), 1 = (x2,[Tinv]x1)
            const int hf  = l & 1;             // half: 0 = copy a, 1 = transform b
            const int ia = o1[p], ib = o2[p];
            const int oa = br ? ib : ia;
            const int ob = br ? ia : ib;
            uint* dst = reinterpret_cast<uint*>(xs + row * LDX + hf * 48);
            if (hf == 0) {
                const float4* g = reinterpret_cast<const float4*>(geoms + (size_t)oa * 48);
                #pragma unroll
                for (int q = 0; q < 12; ++q) {
                    float4 t = g[q];
                    dst[2*q+0] = (uint)f2bf(t.x) | ((uint)f2bf(t.y) << 16);
                    dst[2*q+1] = (uint)f2bf(t.z) | ((uint)f2bf(t.w) << 16);
                }
            } else {
                float v[48];
                const float4* g = reinterpret_cast<const float4*>(geoms + (size_t)ob * 48);
                #pragma unroll
                for (int q = 0; q < 12; ++q) {
                    float4 t = g[q];
                    v[4*q+0] = t.x; v[4*q+1] = t.y; v[4*q+2] = t.z; v[4*q+3] = t.w;
                }
                float M[12];
                if (br == 0) {
                    const float4* T4 = reinterpret_cast<const float4*>(Tg + (size_t)p * 16);
                    float4 r0 = T4[0], r1 = T4[1], r2 = T4[2];
                    M[0]=r0.x; M[1]=r0.y; M[2]=r0.z;  M[3]=r0.w;
                    M[4]=r1.x; M[5]=r1.y; M[6]=r1.z;  M[7]=r1.w;
                    M[8]=r2.x; M[9]=r2.y; M[10]=r2.z; M[11]=r2.w;
                } else {
                    const float* ti = tinv[w * 16 + dp];
                    #pragma unroll
                    for (int i = 0; i < 12; ++i) M[i] = ti[i];
                }
                float o[48];
                #pragma unroll
                for (int m = 0; m < 16; ++m) {
                    float vx = v[3*m+0], vy = v[3*m+1], vz = v[3*m+2];
                    #pragma unroll
                    for (int i = 0; i < 3; ++i)
                        o[3*m+i] = fmaf(M[4*i+0], vx,
                                   fmaf(M[4*i+1], vy,
                                   fmaf(M[4*i+2], vz, M[4*i+3])));
                }
                #pragma unroll
                for (int q = 0; q < 24; ++q)
                    dst[q] = (uint)f2bf(o[2*q]) | ((uint)f2bf(o[2*q+1]) << 16);
            }
        }
        __syncthreads();

        // ===== layer 1: h1 = relu(x @ W1 + b1) ===== (wave-private rows from here on)
        f32x4 acc[2][6];
        #pragma unroll
        for (int mi = 0; mi < 2; ++mi)
            #pragma unroll
            for (int nt = 0; nt < 6; ++nt)
                acc[mi][nt] = (f32x4){0.f, 0.f, 0.f, 0.f};

        bf16x8 afr[2][3];
        #pragma unroll
        for (int mi = 0; mi < 2; ++mi)
            #pragma unroll
            for (int kb = 0; kb < 3; ++kb)
                afr[mi][kb] = *reinterpret_cast<const bf16x8*>(
                    xs + (w*32 + mi*16 + cl) * LDX + kb*32 + (l >> 4) * 8);

        #pragma unroll
        for (int nt = 0; nt < 6; ++nt) {
            bf16x8 bfr[3];
            #pragma unroll
            for (int kb = 0; kb < 3; ++kb)
                bfr[kb] = *reinterpret_cast<const bf16x8*>(
                    w1t + (nt*16 + cl) * LDX + kb*32 + (l >> 4) * 8);
            #pragma unroll
            for (int mi = 0; mi < 2; ++mi)
                #pragma unroll
                for (int kb = 0; kb < 3; ++kb)
                    acc[mi][nt] = __builtin_amdgcn_mfma_f32_16x16x32_bf16(
                        afr[mi][kb], bfr[kb], acc[mi][nt], 0, 0, 0);
        }

        // epilogue 1: bias + relu -> bf16, overwrite xs (own rows only)
        #pragma unroll
        for (int nt = 0; nt < 6; ++nt) {
            float b1v = b1[nt*16 + cl];
            #pragma unroll
            for (int mi = 0; mi < 2; ++mi)
                #pragma unroll
                for (int r = 0; r < 4; ++r) {
                    float h = fmaxf(acc[mi][nt][r] + b1v, 0.f);
                    xs[(w*32 + mi*16 + rg + r) * LDX + nt*16 + cl] = f2bf(h);
                }
        }

        // ===== layer 2: h2 = relu(h1 @ W2 + b2), fused layer 3 dot =====
        f32x4 acc2[2][6];
        #pragma unroll
        for (int mi = 0; mi < 2; ++mi)
            #pragma unroll
            for (int nt = 0; nt < 6; ++nt)
                acc2[mi][nt] = (f32x4){0.f, 0.f, 0.f, 0.f};

        bf16x8 afr2[2][3];
        #pragma unroll
        for (int mi = 0; mi < 2; ++mi)
            #pragma unroll
            for (int kb = 0; kb < 3; ++kb)
                afr2[mi][kb] = *reinterpret_cast<const bf16x8*>(
                    xs + (w*32 + mi*16 + cl) * LDX + kb*32 + (l >> 4) * 8);

        #pragma unroll
        for (int nt = 0; nt < 6; ++nt) {
            bf16x8 bfr[3];
            #pragma unroll
            for (int kb = 0; kb < 3; ++kb)
                bfr[kb] = *reinterpret_cast<const bf16x8*>(
                    w2t + (nt*16 + cl) * LDX + kb*32 + (l >> 4) * 8);
            #pragma unroll
            for (int mi = 0; mi < 2; ++mi)
                #pragma unroll
                for (int kb = 0; kb < 3; ++kb)
                    acc2[mi][nt] = __builtin_amdgcn_mfma_f32_16x16x32_bf16(
                        afr2[mi][kb], bfr[kb], acc2[mi][nt], 0, 0, 0);
        }

        // epilogue 2: relu + W3 dot, butterfly over the 16-col group, write pairs
        float pr[2][4] = {{0.f,0.f,0.f,0.f},{0.f,0.f,0.f,0.f}};
        #pragma unroll
        for (int nt = 0; nt < 6; ++nt) {
            float b2v = b2[nt*16 + cl];
            float w3v = W3[nt*16 + cl];
            #pragma unroll
            for (int mi = 0; mi < 2; ++mi)
                #pragma unroll
                for (int r = 0; r < 4; ++r) {
                    float h = fmaxf(acc2[mi][nt][r] + b2v, 0.f);
                    pr[mi][r] = fmaf(h, w3v, pr[mi][r]);
                }
        }
        #pragma unroll
        for (int s = 1; s < 16; s <<= 1) {
            #pragma unroll
            for (int mi = 0; mi < 2; ++mi)
                #pragma unroll
                for (int r = 0; r < 4; ++r)
                    pr[mi][r] += __shfl_xor(pr[mi][r], s, 64);
        }
        if (cl == 0) {
            float b3v = b3[0];
            #pragma unroll
            for (int mi = 0; mi < 2; ++mi) {
                int row0 = w*32 + mi*16 + rg;          // even
                int pl   = row0 >> 1;                  // even local pair
                float2 res;
                res.x = 0.5f * (pr[mi][0] + pr[mi][1]) + b3v;
                res.y = 0.5f * (pr[mi][2] + pr[mi][3]) + b3v;
                *reinterpret_cast<float2*>(out + (size_t)tile * TP + pl) = res;
            }
        }
    }
}

extern "C" void kernel_launch(void* const* d_in, const int* in_sizes, int n_in,
                              void* d_out, int out_size, void* d_ws, size_t ws_size,
                              hipStream_t stream) {
    const int*   o1    = (const int*)d_in[0];
    const int*   o2    = (const int*)d_in[1];
    const float* T     = (const float*)d_in[2];
    const float* geoms = (const float*)d_in[3];
    const float* W1    = (const float*)d_in[4];
    const float* b1    = (const float*)d_in[5];
    const float* W2    = (const float*)d_in[6];
    const float* b2    = (const float*)d_in[7];
    const float* W3    = (const float*)d_in[8];
    const float* b3    = (const float*)d_in[9];
    float* out = (float*)d_out;
    const int N = in_sizes[0];

    hipLaunchKernelGGL(collision_mfma, dim3(NBLK), dim3(BT), 0, stream,
                       o1, o2, T, geoms, W1, b1, W2, b2, W3, b3, out, N);
}